// Round 1
// baseline (349.425 us; speedup 1.0000x reference)
//
#include <hip/hip_runtime.h>

// Problem constants (from reference): B=4096 batches, D=100 features,
// T=100 timesteps (rows), O=3 outputs.
#define NB 4096
#define ND 100
#define NT 100
#define NO 3
#define PITCH 101   // LDS row pitch: 101*? -> bank stride 5 (coprime 32) => conflict-free

// K1: one block per batch. Stage spikes=(u<x) into LDS, compute
// cur[b][t][o] = dot(spikes[t,:], W[o,:]) + bias[o], write to workspace.
__global__ __launch_bounds__(384) void cur_kernel(
    const float* __restrict__ x, const float* __restrict__ u,
    const float* __restrict__ W, const float* __restrict__ bias,
    float* __restrict__ cur_out)
{
    __shared__ float sp[NT * PITCH];
    __shared__ float Ws[NO * PITCH];
    __shared__ float bs[NO];

    const int b   = blockIdx.x;
    const int tid = threadIdx.x;

    // Stage W ([O][D] row-major) and bias into LDS.
    if (tid < NO * ND) {
        int o = tid / ND;
        int d = tid - o * ND;
        Ws[o * PITCH + d] = W[tid];
    }
    if (tid < NO) bs[tid] = bias[tid];

    // Stage spikes: coalesced float4 loads (D*D=10000, /4 = 2500 vec4).
    // b*10000 floats = 40000 B offset -> 16B aligned.
    const float4* x4 = (const float4*)(x + (size_t)b * (ND * ND));
    const float4* u4 = (const float4*)(u + (size_t)b * (ND * ND));
    for (int i = tid; i < (ND * ND) / 4; i += 384) {
        float4 xv = x4[i];
        float4 uv = u4[i];
        int f   = i * 4;
        int row = f / ND;          // 100 % 4 == 0 -> a float4 never crosses rows
        int col = f - row * ND;
        float* p = &sp[row * PITCH + col];
        p[0] = (uv.x < xv.x) ? 1.0f : 0.0f;
        p[1] = (uv.y < xv.y) ? 1.0f : 0.0f;
        p[2] = (uv.z < xv.z) ? 1.0f : 0.0f;
        p[3] = (uv.w < xv.w) ? 1.0f : 0.0f;
    }
    __syncthreads();

    // 300 tasks: o = tid/100 (wave-quasi-uniform -> W read broadcasts),
    // t = tid%100 (lane-varying -> sp bank stride 5, conflict-free).
    if (tid < NO * NT) {
        int o = tid / NT;
        int t = tid - o * NT;
        const float* sr = &sp[t * PITCH];
        const float* wr = &Ws[o * PITCH];
        float acc = bs[o];
#pragma unroll 10
        for (int d = 0; d < ND; ++d)
            acc = fmaf(sr[d], wr[d], acc);
        // workspace layout: cur[b][t][o]
        cur_out[(size_t)b * (NT * NO) + t * NO + o] = acc;
    }
}

// K2: one thread per (b, o). Sequential leaky scan over t; coalesced writes.
// out[0 .. T*B*O)        = spk_rec [T][B][O]
// out[T*B*O .. 2*T*B*O)  = mem_rec [T][B][O]
__global__ __launch_bounds__(64) void scan_kernel(
    const float* __restrict__ cur,
    const float* __restrict__ beta_p, const float* __restrict__ thr_p,
    float* __restrict__ out)
{
    const int tid = blockIdx.x * 64 + threadIdx.x;   // 0 .. 12287
    const int b = tid / NO;
    const int o = tid - b * NO;
    const float beta = beta_p[0];
    const float thr  = thr_p[0];

    const float* c = cur + (size_t)b * (NT * NO) + o;
    float* mem_rec = out + (size_t)NT * NB * NO;

    float mem = 0.0f;
#pragma unroll 5
    for (int t = 0; t < NT; ++t) {
        float cv = c[t * NO];
        // reset = heaviside(mem_prev - thr); subtract reset*thr
        float rsub = (mem > thr) ? thr : 0.0f;
        // match numpy op order: ((beta*mem) + cur) - reset*thr, no FMA contraction
        mem = __fadd_rn(__fadd_rn(__fmul_rn(beta, mem), cv), -rsub);
        float s = (mem > thr) ? 1.0f : 0.0f;
        out[(size_t)t * (NB * NO) + tid]      = s;
        mem_rec[(size_t)t * (NB * NO) + tid]  = mem;
    }
}

extern "C" void kernel_launch(void* const* d_in, const int* in_sizes, int n_in,
                              void* d_out, int out_size, void* d_ws, size_t ws_size,
                              hipStream_t stream) {
    const float* x    = (const float*)d_in[0];   // [4096,100,100]
    const float* u    = (const float*)d_in[1];   // [4096,100,100]
    const float* W    = (const float*)d_in[2];   // [3,100]
    const float* bias = (const float*)d_in[3];   // [3]
    const float* beta = (const float*)d_in[4];   // scalar
    const float* thr  = (const float*)d_in[5];   // scalar
    float* out = (float*)d_out;

    float* cur_ws = (float*)d_ws;                // 4096*100*3 floats = 4.9 MB

    cur_kernel<<<NB, 384, 0, stream>>>(x, u, W, bias, cur_ws);
    scan_kernel<<<(NB * NO) / 64, 64, 0, stream>>>(cur_ws, beta, thr, out);
}